// Round 10
// baseline (2204.497 us; speedup 1.0000x reference)
//
#include <hip/hip_runtime.h>

// Problem constants (from reference)
constexpr int B_   = 4;
constexpr int N_   = 16384;
constexpr int NOUT = 1170;   // 16384 // 14
constexpr int D_   = 128;
constexpr int O_   = 256;

typedef float f32x2 __attribute__((ext_vector_type(2)));
typedef unsigned long long u64;

// DPP fmax step (validated R4-R9: absmax=0 with this chain).
template <int CTRL>
__device__ __forceinline__ float dpp_fmax(float x) {
  int yi = __builtin_amdgcn_update_dpp(__float_as_int(x), __float_as_int(x),
                                       CTRL, 0xF, 0xF, false);
  return fmaxf(x, __int_as_float(yi));
}

// ---------------- FPS kernel ----------------
// R9 post-mortem: two co-limiting pipes — LDS BW (128 B/thread/step = 1024
// cyc/CU) and VALU issue (~900 cyc). R10 halves the LDS stream by moving ys
// into registers (RA kept 32 array VGPRs resident at VGPR_Count=40; +16 for
// ys stays far under the observed ~96 cap). xs stays in LDS [8][1024] f32x2
// (lane-stride 8B = 2-way bank alias = free, m136). Everything else is the
// validated R9 structure: monotone ownership (thread t owns [16t,16t+16)),
// ballot+ctz winner selection, winner-only rescan, one float4 publish,
// 2 barriers/step.
// Exactness: pk add/mul per-half IEEE f32 (contract off), subtraction as
// +(-c) sign-flip, association ((dx2+dy2)+dz2) = np order; min-index
// tie-break at every tier == np first-max.
constexpr int TPB_FPS = 1024;
constexpr int NPR   = 8;             // f32x2 pairs per thread (16 points)
constexpr int NW    = TPB_FPS / 64;  // 16 waves
constexpr size_t LDS_BYTES = (size_t)N_ * 4 + NW * 4 + 16;  // ~65.6KB

__global__ __launch_bounds__(TPB_FPS, 1)
void fps_kernel(const float* __restrict__ pcd_x,
                int* __restrict__ sel,        // [B, NOUT] (workspace)
                float* __restrict__ out_c) {  // query_c [B, NOUT, 3]
  extern __shared__ char smem_raw[];
  f32x2*  xs2   = (f32x2*)smem_raw;            // [8][1024] 64KB
  float*  s_val = (float*)(xs2 + 8 * 1024);    // [16]
  float4* s_res = (float4*)(s_val + NW);       // [1] {x,y,z,idx}

  const int b = blockIdx.x, t = threadIdx.x;
  const int lane = t & 63, w = t >> 6;
  const float* __restrict__ P = pcd_x + (size_t)b * N_ * 3;

  f32x2 ys[NPR], zs[NPR], dm[NPR];
#pragma unroll
  for (int h = 0; h < NPR; ++h) {
    const int p0 = 16 * t + 2 * h;
    xs2[h * 1024 + t] = f32x2{P[p0 * 3 + 0], P[p0 * 3 + 3]};
    ys[h] = f32x2{P[p0 * 3 + 1], P[p0 * 3 + 4]};
    zs[h] = f32x2{P[p0 * 3 + 2], P[p0 * 3 + 5]};
    dm[h] = f32x2{1e10f, 1e10f};
  }
  __syncthreads();

  float lx = P[0], ly = P[1], lz = P[2];
  if (t == 0) {
    sel[b * NOUT + 0] = 0;
    out_c[((size_t)b * NOUT + 0) * 3 + 0] = lx;
    out_c[((size_t)b * NOUT + 0) * 3 + 1] = ly;
    out_c[((size_t)b * NOUT + 0) * 3 + 2] = lz;
  }

  for (int step = 1; step < NOUT; ++step) {
    // exact negation (sign flip): a - c == a + (-c) bit-exactly in IEEE
    const float nx = __int_as_float(__float_as_int(lx) ^ 0x80000000);
    const float ny = __int_as_float(__float_as_int(ly) ^ 0x80000000);
    const float nz = __int_as_float(__float_as_int(lz) ^ 0x80000000);
    const f32x2 nlx = {nx, nx}, nly = {ny, ny}, nlz = {nz, nz};

    f32x2 bvv = {-1.0f, -1.0f};
    {
#pragma clang fp contract(off)
#pragma unroll
      for (int h = 0; h < NPR; ++h) {
        const f32x2 xv = xs2[h * 1024 + t];   // ds_read_b64 offset:h*8192
        // EXACT np order per component: ((dx*dx + dy*dy) + dz*dz), no FMA
        const f32x2 dx = xv + nlx;
        const f32x2 dy = ys[h] + nly;
        const f32x2 dz = zs[h] + nlz;
        const f32x2 s  = (dx * dx + dy * dy) + dz * dz;
        dm[h] = __builtin_elementwise_min(dm[h], s);
        bvv   = __builtin_elementwise_max(bvv, dm[h]);
      }
    }
    const float bv = fmaxf(bvv.x, bvv.y);

    // pin ys/zs/dm resident across the iteration (R8/R9-validated idiom)
    asm volatile("" : "+v"(ys[0]), "+v"(ys[1]), "+v"(ys[2]), "+v"(ys[3]),
                      "+v"(ys[4]), "+v"(ys[5]), "+v"(ys[6]), "+v"(ys[7]));
    asm volatile("" : "+v"(zs[0]), "+v"(zs[1]), "+v"(zs[2]), "+v"(zs[3]),
                      "+v"(zs[4]), "+v"(zs[5]), "+v"(zs[6]), "+v"(zs[7]));
    asm volatile("" : "+v"(dm[0]), "+v"(dm[1]), "+v"(dm[2]), "+v"(dm[3]),
                      "+v"(dm[4]), "+v"(dm[5]), "+v"(dm[6]), "+v"(dm[7]));

    // wave value max (6 DPP) -> lane0 publishes
    float wm = bv;
    wm = dpp_fmax<0xB1>(wm);   // quad xor1
    wm = dpp_fmax<0x4E>(wm);   // quad xor2
    wm = dpp_fmax<0x141>(wm);  // row_half_mirror
    wm = dpp_fmax<0x140>(wm);  // row_mirror
    wm = dpp_fmax<0x142>(wm);  // row_bcast15
    wm = dpp_fmax<0x143>(wm);  // row_bcast31
    const float wmax =
        __int_as_float(__builtin_amdgcn_readlane(__float_as_int(wm), 63));
    if (lane == 0) s_val[w] = wmax;
    __syncthreads();  // bar1

    // cross-wave value reduce: all lanes, 16 entries, 4 DPP (validated R8/R9)
    const float e = s_val[lane & (NW - 1)];
    float gv = e;
    gv = dpp_fmax<0xB1>(gv);
    gv = dpp_fmax<0x4E>(gv);
    gv = dpp_fmax<0x141>(gv);
    gv = dpp_fmax<0x140>(gv);  // gv = block max (all lanes)

    // first wave achieving gv (lanes 0..15 carry wave w's max)
    const u64 wwm = __ballot((lane < NW) && (e == gv));
    const int ww = __builtin_ctzll(wwm);  // winner wave id (uniform)

    // winning wave only: first achieving lane rescans + publishes
    if (w == ww && bv == gv) {
      const u64 am = __ballot(true);  // achiever lanes (exec mask)
      if (lane == __builtin_ctzll(am)) {
        int bi = 0;
#pragma unroll
        for (int h = NPR - 1; h >= 0; --h) {  // descending: last write = min
          if (dm[h].y == bv) bi = 16 * t + 2 * h + 1;
          if (dm[h].x == bv) bi = 16 * t + 2 * h;
        }
        const int loc = bi & 15, hh = loc >> 1, hf = loc & 1;
        const f32x2 xv = xs2[hh * 1024 + t];
        const float wx = hf ? xv.y : xv.x;
        const float wy = hf ? ys[hh].y : ys[hh].x;
        const float wz = hf ? zs[hh].y : zs[hh].x;
        s_res[0] = make_float4(wx, wy, wz, __int_as_float(bi));
        sel[b * NOUT + step] = bi;                       // off critical path
        out_c[((size_t)b * NOUT + step) * 3 + 0] = wx;
        out_c[((size_t)b * NOUT + step) * 3 + 1] = wy;
        out_c[((size_t)b * NOUT + step) * 3 + 2] = wz;
      }
    }
    __syncthreads();  // bar2

    const float4 r = s_res[0];  // same-address broadcast
    lx = r.x; ly = r.y; lz = r.z;
  }
}

// ---------------- projection + gathers ----------------
constexpr int TPB_PROJ = 256;
constexpr int RPB = 4;

__global__ __launch_bounds__(TPB_PROJ)
void proj_kernel(const float* __restrict__ tgt,
                 const float* __restrict__ pcd_v,
                 const float* __restrict__ W,
                 const float* __restrict__ bias,
                 const int* __restrict__ sel,
                 float* __restrict__ out_f,    // [B*NOUT, 256]
                 float* __restrict__ out_v) {  // [B*NOUT, 9]
  const int t = threadIdx.x;
  const int row0 = blockIdx.x * RPB;
  __shared__ float sA[RPB * D_];
  __shared__ int   sIdx[RPB];
  if (t < RPB) {
    const int row = row0 + t;
    const int b = row / NOUT;
    sIdx[t] = b * N_ + sel[row];
  }
  __syncthreads();
#pragma unroll
  for (int l = 0; l < RPB * D_ / TPB_PROJ; ++l) {
    const int e = t + l * TPB_PROJ;
    const int r = e >> 7, k = e & (D_ - 1);
    sA[e] = tgt[(size_t)sIdx[r] * D_ + k];
  }
  __syncthreads();
  float acc0 = 0.f, acc1 = 0.f, acc2 = 0.f, acc3 = 0.f;
#pragma unroll 8
  for (int k = 0; k < D_; ++k) {
    const float w = W[k * O_ + t];
    acc0 = fmaf(sA[0 * D_ + k], w, acc0);
    acc1 = fmaf(sA[1 * D_ + k], w, acc1);
    acc2 = fmaf(sA[2 * D_ + k], w, acc2);
    acc3 = fmaf(sA[3 * D_ + k], w, acc3);
  }
  const float bb = bias[t];
  out_f[(size_t)(row0 + 0) * O_ + t] = acc0 + bb;
  out_f[(size_t)(row0 + 1) * O_ + t] = acc1 + bb;
  out_f[(size_t)(row0 + 2) * O_ + t] = acc2 + bb;
  out_f[(size_t)(row0 + 3) * O_ + t] = acc3 + bb;
  if (t < RPB * 9) {
    const int r = t / 9, e = t - r * 9;
    out_v[(size_t)(row0 + r) * 9 + e] = pcd_v[(size_t)sIdx[r] * 9 + e];
  }
}

extern "C" void kernel_launch(void* const* d_in, const int* in_sizes, int n_in,
                              void* d_out, int out_size, void* d_ws, size_t ws_size,
                              hipStream_t stream) {
  const float* tgt   = (const float*)d_in[0];  // [4,16384,128]
  const float* pcd_x = (const float*)d_in[1];  // [4,16384,3]
  const float* pcd_v = (const float*)d_in[2];  // [4,16384,3,3]
  const float* W     = (const float*)d_in[3];  // [128,256]
  const float* bias  = (const float*)d_in[4];  // [256]

  float* out   = (float*)d_out;
  float* out_f = out;                                   // [4,1170,256]
  float* out_c = out + (size_t)B_ * NOUT * O_;          // [4,1170,3]
  float* out_v = out_c + (size_t)B_ * NOUT * 3;         // [4,1170,3,3]

  int* sel = (int*)d_ws;  // [4,1170] int32

  hipLaunchKernelGGL(fps_kernel, dim3(B_), dim3(TPB_FPS), LDS_BYTES, stream,
                     pcd_x, sel, out_c);
  hipLaunchKernelGGL(proj_kernel, dim3(B_ * NOUT / RPB), dim3(TPB_PROJ), 0, stream,
                     tgt, pcd_v, W, bias, sel, out_f, out_v);
}

// Round 11
// 1995.168 us; speedup vs baseline: 1.1049x; 1.1049x over previous
//
#include <hip/hip_runtime.h>

// Problem constants (from reference)
constexpr int B_   = 4;
constexpr int N_   = 16384;
constexpr int NOUT = 1170;   // 16384 // 14
constexpr int D_   = 128;
constexpr int O_   = 256;

typedef float f32x2 __attribute__((ext_vector_type(2)));
typedef unsigned long long u64;

// DPP fmax step (validated R4-R10: absmax=0 with this chain).
template <int CTRL>
__device__ __forceinline__ float dpp_fmax(float x) {
  int yi = __builtin_amdgcn_update_dpp(__float_as_int(x), __float_as_int(x),
                                       CTRL, 0xF, 0xF, false);
  return fmaxf(x, __int_as_float(yi));
}

// AGPR park/fetch: this kernel has no MFMA, so the unified AGPR file is
// idle — values written there by opaque volatile asm cannot be sunk,
// rematerialized, or profitably spilled by the RA (which refuses to keep
// >32 array VGPRs resident: R8/R9 ok at 32, R10 failed at 48).
#define AWRITE(dst, src) \
  asm volatile("v_accvgpr_write_b32 %0, %1" : "=a"(dst) : "v"(src))
#define AREAD(dst, src) \
  asm volatile("v_accvgpr_read_b32 %0, %1" : "=v"(dst) : "a"(src))

// ---------------- FPS kernel ----------------
// R9 post-mortem: LDS-stream-bound (128 B/thread/step = 1024 cyc/CU of LDS
// pipe occupancy; active-CU VALUBusy only 64%). R11 deletes the stream:
// x,y coords live in AGPRs (32/thread), pulled per step with 32
// v_accvgpr_read (VALU-only, no lgkmcnt, no LDS BW). zs+dm stay in VGPRs
// (32 regs — the RA's proven-stable array budget). LDS keeps a write-once
// xy[16384] table used ONLY for the 8 B/step winner-coord broadcast.
// Reduce tail is the validated R9 path: monotone ownership (thread t owns
// [16t,16t+16)), 6-DPP wave max, ballot+ctz winner wave, winner-only
// rescan, {z,idx} publish, 2 barriers/step.
// Exactness: pk add/mul per-half IEEE f32 (contract off), subtraction as
// +(-c) sign-flip, association ((dx2+dy2)+dz2) = np order; min-index
// tie-break at every tier == np first-max.
constexpr int TPB_FPS = 1024;
constexpr int NPR   = 8;             // f32x2 pairs per thread (16 points)
constexpr int NW    = TPB_FPS / 64;  // 16 waves
constexpr size_t LDS_BYTES = (size_t)N_ * 8 + NW * 4 + 16;  // ~131.2KB

__global__ __launch_bounds__(TPB_FPS, 1)
void fps_kernel(const float* __restrict__ pcd_x,
                int* __restrict__ sel,        // [B, NOUT] (workspace)
                float* __restrict__ out_c) {  // query_c [B, NOUT, 3]
  extern __shared__ char smem_raw[];
  f32x2*  xy    = (f32x2*)smem_raw;            // [16384] {x,y} lookup, 128KB
  float*  s_val = (float*)(xy + N_);           // [16]
  float2* s_res = (float2*)(s_val + NW);       // [1] {z, idx}

  const int b = blockIdx.x, t = threadIdx.x;
  const int lane = t & 63, w = t >> 6;
  const float* __restrict__ P = pcd_x + (size_t)b * N_ * 3;

  float ax[2 * NPR], ay[2 * NPR];   // AGPR-class (only touched via asm)
  f32x2 zs[NPR], dm[NPR];
#pragma unroll
  for (int h = 0; h < NPR; ++h) {
    const int p0 = 16 * t + 2 * h;
    const float x0 = P[p0 * 3 + 0], y0 = P[p0 * 3 + 1], z0 = P[p0 * 3 + 2];
    const float x1 = P[p0 * 3 + 3], y1 = P[p0 * 3 + 4], z1 = P[p0 * 3 + 5];
    xy[p0]     = f32x2{x0, y0};
    xy[p0 + 1] = f32x2{x1, y1};
    AWRITE(ax[2 * h], x0);  AWRITE(ax[2 * h + 1], x1);
    AWRITE(ay[2 * h], y0);  AWRITE(ay[2 * h + 1], y1);
    zs[h] = f32x2{z0, z1};
    dm[h] = f32x2{1e10f, 1e10f};
  }
  __syncthreads();

  float lx = P[0], ly = P[1], lz = P[2];
  if (t == 0) {
    sel[b * NOUT + 0] = 0;
    out_c[((size_t)b * NOUT + 0) * 3 + 0] = lx;
    out_c[((size_t)b * NOUT + 0) * 3 + 1] = ly;
    out_c[((size_t)b * NOUT + 0) * 3 + 2] = lz;
  }

  for (int step = 1; step < NOUT; ++step) {
    // exact negation (sign flip): a - c == a + (-c) bit-exactly in IEEE
    const float nx = __int_as_float(__float_as_int(lx) ^ 0x80000000);
    const float ny = __int_as_float(__float_as_int(ly) ^ 0x80000000);
    const float nz = __int_as_float(__float_as_int(lz) ^ 0x80000000);
    const f32x2 nlx = {nx, nx}, nly = {ny, ny}, nlz = {nz, nz};

    f32x2 bvv = {-1.0f, -1.0f};
    {
#pragma clang fp contract(off)
#pragma unroll
      for (int h = 0; h < NPR; ++h) {
        float xl, xh, yl, yh;
        AREAD(xl, ax[2 * h]);  AREAD(xh, ax[2 * h + 1]);
        AREAD(yl, ay[2 * h]);  AREAD(yh, ay[2 * h + 1]);
        const f32x2 xv = {xl, xh};
        const f32x2 yv = {yl, yh};
        // EXACT np order per component: ((dx*dx + dy*dy) + dz*dz), no FMA
        const f32x2 dx = xv + nlx;
        const f32x2 dy = yv + nly;
        const f32x2 dz = zs[h] + nlz;
        const f32x2 s  = (dx * dx + dy * dy) + dz * dz;
        dm[h] = __builtin_elementwise_min(dm[h], s);
        bvv   = __builtin_elementwise_max(bvv, dm[h]);
      }
    }
    const float bv = fmaxf(bvv.x, bvv.y);

    // pin zs/dm resident across the iteration (R8/R9-validated idiom)
    asm volatile("" : "+v"(zs[0]), "+v"(zs[1]), "+v"(zs[2]), "+v"(zs[3]),
                      "+v"(zs[4]), "+v"(zs[5]), "+v"(zs[6]), "+v"(zs[7]));
    asm volatile("" : "+v"(dm[0]), "+v"(dm[1]), "+v"(dm[2]), "+v"(dm[3]),
                      "+v"(dm[4]), "+v"(dm[5]), "+v"(dm[6]), "+v"(dm[7]));

    // wave value max (6 DPP) -> lane0 publishes
    float wm = bv;
    wm = dpp_fmax<0xB1>(wm);   // quad xor1
    wm = dpp_fmax<0x4E>(wm);   // quad xor2
    wm = dpp_fmax<0x141>(wm);  // row_half_mirror
    wm = dpp_fmax<0x140>(wm);  // row_mirror
    wm = dpp_fmax<0x142>(wm);  // row_bcast15
    wm = dpp_fmax<0x143>(wm);  // row_bcast31
    const float wmax =
        __int_as_float(__builtin_amdgcn_readlane(__float_as_int(wm), 63));
    if (lane == 0) s_val[w] = wmax;
    __syncthreads();  // bar1

    // cross-wave value reduce: all lanes, 16 entries, 4 DPP (validated)
    const float e = s_val[lane & (NW - 1)];
    float gv = e;
    gv = dpp_fmax<0xB1>(gv);
    gv = dpp_fmax<0x4E>(gv);
    gv = dpp_fmax<0x141>(gv);
    gv = dpp_fmax<0x140>(gv);  // gv = block max (all lanes)

    // first wave achieving gv (lanes 0..15 carry wave w's max)
    const u64 wwm = __ballot((lane < NW) && (e == gv));
    const int ww = __builtin_ctzll(wwm);  // winner wave id (uniform)

    // winning wave only: first achieving lane rescans + publishes {z, idx}
    if (w == ww && bv == gv) {
      const u64 am = __ballot(true);  // achiever lanes (exec mask)
      if (lane == __builtin_ctzll(am)) {
        int bi = 0;
#pragma unroll
        for (int h = NPR - 1; h >= 0; --h) {  // descending: last write = min
          if (dm[h].y == bv) bi = 16 * t + 2 * h + 1;
          if (dm[h].x == bv) bi = 16 * t + 2 * h;
        }
        const int loc = bi & 15, hh = loc >> 1, hf = loc & 1;
        const float wz = hf ? zs[hh].y : zs[hh].x;  // R9-proven dynamic sel
        s_res[0] = make_float2(wz, __int_as_float(bi));
        sel[b * NOUT + step] = bi;  // off critical path
      }
    }
    __syncthreads();  // bar2

    const float2 r = s_res[0];          // same-address broadcast
    const int ri = __float_as_int(r.y);
    const f32x2 xyv = xy[ri];           // 8B/step broadcast lookup
    lx = xyv.x; ly = xyv.y; lz = r.x;
    if (t == 0) {
      out_c[((size_t)b * NOUT + step) * 3 + 0] = lx;
      out_c[((size_t)b * NOUT + step) * 3 + 1] = ly;
      out_c[((size_t)b * NOUT + step) * 3 + 2] = lz;
    }
  }
}

// ---------------- projection + gathers ----------------
constexpr int TPB_PROJ = 256;
constexpr int RPB = 4;

__global__ __launch_bounds__(TPB_PROJ)
void proj_kernel(const float* __restrict__ tgt,
                 const float* __restrict__ pcd_v,
                 const float* __restrict__ W,
                 const float* __restrict__ bias,
                 const int* __restrict__ sel,
                 float* __restrict__ out_f,    // [B*NOUT, 256]
                 float* __restrict__ out_v) {  // [B*NOUT, 9]
  const int t = threadIdx.x;
  const int row0 = blockIdx.x * RPB;
  __shared__ float sA[RPB * D_];
  __shared__ int   sIdx[RPB];
  if (t < RPB) {
    const int row = row0 + t;
    const int b = row / NOUT;
    sIdx[t] = b * N_ + sel[row];
  }
  __syncthreads();
#pragma unroll
  for (int l = 0; l < RPB * D_ / TPB_PROJ; ++l) {
    const int e = t + l * TPB_PROJ;
    const int r = e >> 7, k = e & (D_ - 1);
    sA[e] = tgt[(size_t)sIdx[r] * D_ + k];
  }
  __syncthreads();
  float acc0 = 0.f, acc1 = 0.f, acc2 = 0.f, acc3 = 0.f;
#pragma unroll 8
  for (int k = 0; k < D_; ++k) {
    const float w = W[k * O_ + t];
    acc0 = fmaf(sA[0 * D_ + k], w, acc0);
    acc1 = fmaf(sA[1 * D_ + k], w, acc1);
    acc2 = fmaf(sA[2 * D_ + k], w, acc2);
    acc3 = fmaf(sA[3 * D_ + k], w, acc3);
  }
  const float bb = bias[t];
  out_f[(size_t)(row0 + 0) * O_ + t] = acc0 + bb;
  out_f[(size_t)(row0 + 1) * O_ + t] = acc1 + bb;
  out_f[(size_t)(row0 + 2) * O_ + t] = acc2 + bb;
  out_f[(size_t)(row0 + 3) * O_ + t] = acc3 + bb;
  if (t < RPB * 9) {
    const int r = t / 9, e = t - r * 9;
    out_v[(size_t)(row0 + r) * 9 + e] = pcd_v[(size_t)sIdx[r] * 9 + e];
  }
}

extern "C" void kernel_launch(void* const* d_in, const int* in_sizes, int n_in,
                              void* d_out, int out_size, void* d_ws, size_t ws_size,
                              hipStream_t stream) {
  const float* tgt   = (const float*)d_in[0];  // [4,16384,128]
  const float* pcd_x = (const float*)d_in[1];  // [4,16384,3]
  const float* pcd_v = (const float*)d_in[2];  // [4,16384,3,3]
  const float* W     = (const float*)d_in[3];  // [128,256]
  const float* bias  = (const float*)d_in[4];  // [256]

  float* out   = (float*)d_out;
  float* out_f = out;                                   // [4,1170,256]
  float* out_c = out + (size_t)B_ * NOUT * O_;          // [4,1170,3]
  float* out_v = out_c + (size_t)B_ * NOUT * 3;         // [4,1170,3,3]

  int* sel = (int*)d_ws;  // [4,1170] int32

  hipLaunchKernelGGL(fps_kernel, dim3(B_), dim3(TPB_FPS), LDS_BYTES, stream,
                     pcd_x, sel, out_c);
  hipLaunchKernelGGL(proj_kernel, dim3(B_ * NOUT / RPB), dim3(TPB_PROJ), 0, stream,
                     tgt, pcd_v, W, bias, sel, out_f, out_v);
}